// Round 15
// baseline (538.159 us; speedup 1.0000x reference)
//
#include <hip/hip_runtime.h>
#include <math.h>

#define NN 50000
#define NE 800000
#define EMB 128
#define HID 256
#define NF 7
#define EF 5
#define NL 5
#define BN_EPS 1e-5f
#define NREP 32     // stats replicas to kill same-line atomic serialization
#define SCAN_B 196  // ceil(NN/256)
#define NBUCK 49    // ceil(NN/1024) coarse dst-buckets for the 2-phase fill

typedef _Float16 f16x8 __attribute__((ext_vector_type(8)));
typedef _Float16 f16x2 __attribute__((ext_vector_type(2)));
typedef __attribute__((ext_vector_type(4))) float f32x4;

// fp16 pack/unpack
__device__ inline unsigned pkh2(float a, float b) {
    union { unsigned v; _Float16 h[2]; } x;
    x.h[0] = (_Float16)a; x.h[1] = (_Float16)b;
    return x.v;
}
__device__ inline float2 uph2(unsigned u) {
    union { unsigned v; _Float16 h[2]; } x; x.v = u;
    return make_float2((float)x.h[0], (float)x.h[1]);
}
__device__ inline unsigned short f2h_bits(float f) {
    _Float16 h = (_Float16)f;
    return __builtin_bit_cast(unsigned short, h);
}
__device__ inline float h_bits2f(unsigned short b) {
    return (float)__builtin_bit_cast(_Float16, b);
}
__device__ inline f16x2 as_h2(unsigned u) { return __builtin_bit_cast(f16x2, u); }

// ---------------------------------------------------------------------------
// k_prep: block 0 computes bias-sum vectors; all blocks zero CSR counts/cursor
// and ALL per-layer BN-stats replicas (zeroed once for all NL layers).
// ---------------------------------------------------------------------------
__global__ void k_prep(const float* __restrict__ b_x, const float* __restrict__ b_e,
                       float* __restrict__ bsum_x, float* __restrict__ bsum_e,
                       int* __restrict__ counts, int* __restrict__ cursor,
                       float* __restrict__ stats) {
    int tid = threadIdx.x;
    if (blockIdx.x == 0 && tid < EMB) {
        float s = 0.f;
        for (int f = 0; f < NF; ++f) s += b_x[f * EMB + tid];
        bsum_x[tid] = s;
        for (int l = 0; l < NL; ++l) {
            float se = 0.f;
            for (int f = 0; f < EF; ++f) se += b_e[(l * EF + f) * EMB + tid];
            bsum_e[l * EMB + tid] = se;
        }
    }
    int gid = blockIdx.x * blockDim.x + tid;
    int stride = gridDim.x * blockDim.x;
    for (int i = gid; i < NN; i += stride) { counts[i] = 0; cursor[i] = 0; }
    const int STOT = NL * NREP * 2 * EMB;
    for (int i = gid; i < STOT; i += stride) stats[i] = 0.f;
}

// ---------------------------------------------------------------------------
// k_prepw: fragment-pack + fp16 hi/lo split of weights (combined rel ~2^-22).
// W1p layout: [L][wave(4)][h2(4)][kk(4)][lane(64)][j(8)]  (lane-contiguous 16B)
// W2p layout: [L][wave(4)][o2(2)][kk(8)][lane(64)][j(8)]
// ---------------------------------------------------------------------------
__global__ void k_prepw(const float* __restrict__ W1, const float* __restrict__ W2,
                        unsigned short* __restrict__ W1ph, unsigned short* __restrict__ W1pl,
                        unsigned short* __restrict__ W2ph, unsigned short* __restrict__ W2pl) {
    const int TOT = NL * EMB * HID;   // 163840 per matrix
    int gid = blockIdx.x * blockDim.x + threadIdx.x;
    if (gid < TOT) {
        int l = gid / (EMB * HID);
        int r = gid % (EMB * HID);             // 32768
        int w = r >> 13;                       // /8192
        int rem = r & 8191;
        int h2 = rem >> 11;                    // /2048
        int rem2 = rem & 2047;
        int kk = rem2 >> 9;                    // /512
        int rem3 = rem2 & 511;
        int lane = rem3 >> 3;
        int j = rem3 & 7;
        int hc = w * 64 + h2 * 16 + (lane & 15);
        int k = kk * 32 + (lane >> 4) * 8 + j;
        float wv = W1[((size_t)l * EMB + k) * HID + hc];
        unsigned short hi = f2h_bits(wv);
        W1ph[gid] = hi;
        W1pl[gid] = f2h_bits(wv - h_bits2f(hi));
    } else if (gid < 2 * TOT) {
        int g = gid - TOT;
        int l = g / (EMB * HID);
        int r = g % (EMB * HID);
        int w = r >> 13;
        int rem = r & 8191;
        int o2 = rem >> 12;                    // /4096
        int rem2 = rem & 4095;
        int kk = rem2 >> 9;
        int rem3 = rem2 & 511;
        int lane = rem3 >> 3;
        int j = rem3 & 7;
        int oc = w * 32 + o2 * 16 + (lane & 15);
        int k2 = kk * 32 + (lane >> 4) * 8 + j;
        float wv = W2[((size_t)l * HID + k2) * EMB + oc];
        unsigned short hi = f2h_bits(wv);
        W2ph[g] = hi;
        W2pl[g] = f2h_bits(wv - h_bits2f(hi));
    }
}

// ---------------------------------------------------------------------------
// k_init: h(fp16) = x @ W_x + bsum_x  (32 threads/node, 4 cols each)
// ---------------------------------------------------------------------------
__global__ void k_init(const float* __restrict__ x, const float* __restrict__ W_x,
                       const float* __restrict__ bsum_x, unsigned short* __restrict__ h16) {
    int gid = blockIdx.x * blockDim.x + threadIdx.x;
    int v = gid >> 5;
    if (v >= NN) return;
    int c = (gid & 31) << 2;
    float4 acc = *(const float4*)(bsum_x + c);
    #pragma unroll
    for (int f = 0; f < NF; ++f) {
        float xv = x[(size_t)v * NF + f];
        float4 w = *(const float4*)(W_x + f * EMB + c);
        acc.x += xv * w.x; acc.y += xv * w.y; acc.z += xv * w.z; acc.w += xv * w.w;
    }
    uint2 p = make_uint2(pkh2(acc.x, acc.y), pkh2(acc.z, acc.w));
    *(uint2*)(h16 + (size_t)v * EMB + c) = p;
}

// ---------------------------------------------------------------------------
// CSR build: histogram of dst, 3-phase multi-block scan
// ---------------------------------------------------------------------------
__global__ void k_hist(const int* __restrict__ dst, int* __restrict__ counts) {
    int e = blockIdx.x * blockDim.x + threadIdx.x;
    if (e < NE) atomicAdd(&counts[dst[e]], 1);
}

__global__ void k_scan1(const int* __restrict__ counts, int* __restrict__ bsum) {
    int tid = threadIdx.x;
    int i = blockIdx.x * 256 + tid;
    int v = (i < NN) ? counts[i] : 0;
    #pragma unroll
    for (int off = 1; off < 64; off <<= 1) v += __shfl_xor(v, off, 64);
    __shared__ int ws[4];
    if ((tid & 63) == 0) ws[tid >> 6] = v;
    __syncthreads();
    if (tid == 0) bsum[blockIdx.x] = ws[0] + ws[1] + ws[2] + ws[3];
}

__global__ void k_scan2(const int* __restrict__ bsum, int* __restrict__ bpre,
                        int* __restrict__ row_start) {
    int tid = threadIdx.x;  // 256 threads
    int x = (tid < SCAN_B) ? bsum[tid] : 0;
    int lane = tid & 63, wv = tid >> 6;
    int v = x;
    #pragma unroll
    for (int off = 1; off < 64; off <<= 1) {
        int t = __shfl_up(v, off, 64);
        if (lane >= off) v += t;
    }
    __shared__ int wsum[4];
    if (lane == 63) wsum[wv] = v;
    __syncthreads();
    int woff = 0;
    #pragma unroll
    for (int w = 0; w < 4; ++w) if (w < wv) woff += wsum[w];
    int incl = v + woff;
    if (tid < SCAN_B) bpre[tid] = incl - x;
    if (tid == 255) row_start[NN] = incl;
}

// scan3 also seeds the coarse-bucket cursors: bcur[b] = row_start[b*1024]
__global__ void k_scan3(const int* __restrict__ counts, const int* __restrict__ bpre,
                        int* __restrict__ row_start, int* __restrict__ bcur) {
    int tid = threadIdx.x;
    int i = blockIdx.x * 256 + tid;
    int x = (i < NN) ? counts[i] : 0;
    int lane = tid & 63, wv = tid >> 6;
    int v = x;
    #pragma unroll
    for (int off = 1; off < 64; off <<= 1) {
        int t = __shfl_up(v, off, 64);
        if (lane >= off) v += t;
    }
    __shared__ int wsum[4];
    if (lane == 63) wsum[wv] = v;
    __syncthreads();
    int woff = 0;
    #pragma unroll
    for (int w = 0; w < 4; ++w) if (w < wv) woff += wsum[w];
    if (i < NN) {
        int rs = bpre[blockIdx.x] + v + woff - x;
        row_start[i] = rs;
        if ((i & 1023) == 0) bcur[i >> 10] = rs;
    }
}

// ---------------------------------------------------------------------------
// 2-phase fill: k_bucket = LDS-histogram radix partition into NBUCK coarse
// dst-buckets (contiguous appends, no sector amplification);
// k_place = scatter within an L2-resident ~200KB bucket range.
// Record: {src, h(a0,a1), h(a2,a3), h(a4) | dst<<16}  (dst < 2^16).
// ---------------------------------------------------------------------------
#define BPB 2048   // edges per block
__global__ __launch_bounds__(256) void k_bucket(
        const int* __restrict__ src, const int* __restrict__ dst,
        const float* __restrict__ edge_attr,
        int* __restrict__ bcur, uint4* __restrict__ grouped) {
    __shared__ int lcnt[NBUCK];
    __shared__ int lbase[NBUCK];
    int tid = threadIdx.x;
    if (tid < NBUCK) lcnt[tid] = 0;
    __syncthreads();
    int base = blockIdx.x * BPB;
    int b_[8];
    int d_[8];
    #pragma unroll
    for (int k = 0; k < 8; ++k) {
        int e = base + k * 256 + tid;
        if (e < NE) {
            int d = dst[e];
            d_[k] = d;
            b_[k] = d >> 10;
            atomicAdd(&lcnt[b_[k]], 1);
        } else b_[k] = -1;
    }
    __syncthreads();
    if (tid < NBUCK) {
        lbase[tid] = (lcnt[tid] > 0) ? atomicAdd(&bcur[tid], lcnt[tid]) : 0;
        lcnt[tid] = 0;
    }
    __syncthreads();
    #pragma unroll
    for (int k = 0; k < 8; ++k) {
        int e = base + k * 256 + tid;
        if (e < NE) {
            int b = b_[k];
            int off = lbase[b] + atomicAdd(&lcnt[b], 1);
            const float* ea = edge_attr + (size_t)e * EF;
            uint4 pk;
            pk.x = (unsigned)src[e];
            pk.y = pkh2(ea[0], ea[1]);
            pk.z = pkh2(ea[2], ea[3]);
            pk.w = (unsigned)f2h_bits(ea[4]) | ((unsigned)d_[k] << 16);
            grouped[off] = pk;
        }
    }
}

__global__ void k_place(const uint4* __restrict__ grouped,
                        const int* __restrict__ row_start, int* __restrict__ cursor,
                        uint4* __restrict__ sorted_pk) {
    int e = blockIdx.x * blockDim.x + threadIdx.x;
    if (e >= NE) return;
    uint4 pk = grouped[e];
    int d = (int)(pk.w >> 16);
    int pos = atomicAdd(&cursor[d], 1);
    sorted_pk[row_start[d] + pos] = pk;
}

// ---------------------------------------------------------------------------
// k_esum (once): per node, sum incoming edge attrs -> attsum[v][8] =
// {a0..a4, deg, 0, 0}; emit compact sorted_srcc[e] (sequential write).
// ---------------------------------------------------------------------------
__global__ void k_esum(const uint4* __restrict__ sorted_pk,
                       const int* __restrict__ row_start,
                       float* __restrict__ attsum, int* __restrict__ sorted_srcc) {
    int v = blockIdx.x * blockDim.x + threadIdx.x;
    if (v >= NN) return;
    int e0 = row_start[v], e1 = row_start[v + 1];
    float s0 = 0.f, s1 = 0.f, s2 = 0.f, s3 = 0.f, s4 = 0.f;
    for (int e = e0; e < e1; ++e) {
        uint4 pk = sorted_pk[e];
        sorted_srcc[e] = (int)pk.x;
        float2 a01 = uph2(pk.y), a23 = uph2(pk.z);
        s0 += a01.x; s1 += a01.y; s2 += a23.x; s3 += a23.y;
        s4 += h_bits2f((unsigned short)(pk.w & 0xffffu));
    }
    float* o = attsum + (size_t)v * 8;
    *(float4*)(o) = make_float4(s0, s1, s2, s3);
    *(float4*)(o + 4) = make_float4(s4, (float)(e1 - e0), 0.f, 0.f);
}

// ---------------------------------------------------------------------------
// k_agg: agg[v] = h[v] + (deg+1)*bs + attsum[v]@W_e + sum_e h[src].
// r10 PMC implied ~30.6us/layer at 3.1 TB/s gather throughput -> duty-cycle
// bound (loads in flight only ~1/3 of wave lifetime). r11: TWO nodes per
// wave (vA=2w, vB=2w+1; NN even so both valid): both nodes' remainder
// bursts are flattened to unified 23-slot clamped index/gather bursts and
// issued back-to-back (idxA,idxB,gatherA,gatherB) -> 2 round-trips cover 2
// nodes, up to 46 loads in flight/wave. Accumulation keeps the exact r10
// per-node grouping (tree16/tree8 + guarded serial) -> bitwise identical.
// Grid halves to 6250 blocks. VGPR rises (~130-160, watch profile).
// ---------------------------------------------------------------------------
#define IDXQ(N, k) \
    int s##N##k = __builtin_amdgcn_readfirstlane( \
        sorted_srcc[(e##N + k < e1##N) ? (e##N + k) : cb##N]);
#define GTHQ(N, k) \
    unsigned u##N##k = *(const unsigned*)(h16 + (size_t)s##N##k * EMB + c);
#define ACCG(N, k) \
    if (e##N + k < e1##N) { float2 g = uph2(u##N##k); ax##N += g.x; ay##N += g.y; }

__global__ __launch_bounds__(256) void k_agg(
        const unsigned short* __restrict__ h16, const int* __restrict__ sorted_srcc,
        const float* __restrict__ attsum,
        const float* __restrict__ W_e_l, const float* __restrict__ bsum_e_l,
        const int* __restrict__ row_start,
        unsigned short* __restrict__ agg16) {
    int tid = threadIdx.x;
    int gid = blockIdx.x * 256 + tid;
    int w = gid >> 6;                 // pair index
    int vA = w << 1;
    if (vA >= NN) return;
    int vB = vA + 1;                  // NN even -> always valid
    int c = (gid & 63) << 1;
    float2 we0 = *(const float2*)(W_e_l + 0 * EMB + c);
    float2 we1 = *(const float2*)(W_e_l + 1 * EMB + c);
    float2 we2 = *(const float2*)(W_e_l + 2 * EMB + c);
    float2 we3 = *(const float2*)(W_e_l + 3 * EMB + c);
    float2 we4 = *(const float2*)(W_e_l + 4 * EMB + c);
    float2 bs = *(const float2*)(bsum_e_l + c);
    float2 hvA = uph2(*(const unsigned*)(h16 + (size_t)vA * EMB + c));
    float2 hvB = uph2(*(const unsigned*)(h16 + (size_t)vB * EMB + c));
    const float* atA = attsum + (size_t)vA * 8;
    const float* atB = attsum + (size_t)vB * 8;
    float4 a03A = *(const float4*)(atA);
    float2 a45A = *(const float2*)(atA + 4);
    float4 a03B = *(const float4*)(atB);
    float2 a45B = *(const float2*)(atB + 4);
    int e0A = row_start[vA];
    int e1A = row_start[vA + 1];
    int e1B = row_start[vA + 2];
    int e0B = e1A;
    float axA = hvA.x + (a45A.y + 1.f) * bs.x
              + a03A.x*we0.x + a03A.y*we1.x + a03A.z*we2.x + a03A.w*we3.x + a45A.x*we4.x;
    float ayA = hvA.y + (a45A.y + 1.f) * bs.y
              + a03A.x*we0.y + a03A.y*we1.y + a03A.z*we2.y + a03A.w*we3.y + a45A.x*we4.y;
    float axB = hvB.x + (a45B.y + 1.f) * bs.x
              + a03B.x*we0.x + a03B.y*we1.x + a03B.z*we2.x + a03B.w*we3.x + a45B.x*we4.x;
    float ayB = hvB.y + (a45B.y + 1.f) * bs.y
              + a03B.x*we0.y + a03B.y*we1.y + a03B.z*we2.y + a03B.w*we3.y + a45B.x*we4.y;
    int eA = e0A, eB = e0B;
    // bulk 16-batches while >=24 remain (rare: deg>=24, ~3% of nodes)
    auto bulk16 = [&](int& e, int e1, float& ax, float& ay) {
        for (; e + 24 <= e1; e += 16) {
            int s0 = __builtin_amdgcn_readfirstlane(sorted_srcc[e + 0]);
            int s1 = __builtin_amdgcn_readfirstlane(sorted_srcc[e + 1]);
            int s2 = __builtin_amdgcn_readfirstlane(sorted_srcc[e + 2]);
            int s3 = __builtin_amdgcn_readfirstlane(sorted_srcc[e + 3]);
            int s4 = __builtin_amdgcn_readfirstlane(sorted_srcc[e + 4]);
            int s5 = __builtin_amdgcn_readfirstlane(sorted_srcc[e + 5]);
            int s6 = __builtin_amdgcn_readfirstlane(sorted_srcc[e + 6]);
            int s7 = __builtin_amdgcn_readfirstlane(sorted_srcc[e + 7]);
            int s8 = __builtin_amdgcn_readfirstlane(sorted_srcc[e + 8]);
            int s9 = __builtin_amdgcn_readfirstlane(sorted_srcc[e + 9]);
            int sa = __builtin_amdgcn_readfirstlane(sorted_srcc[e + 10]);
            int sb = __builtin_amdgcn_readfirstlane(sorted_srcc[e + 11]);
            int sc = __builtin_amdgcn_readfirstlane(sorted_srcc[e + 12]);
            int sd = __builtin_amdgcn_readfirstlane(sorted_srcc[e + 13]);
            int se = __builtin_amdgcn_readfirstlane(sorted_srcc[e + 14]);
            int sf = __builtin_amdgcn_readfirstlane(sorted_srcc[e + 15]);
            unsigned u0 = *(const unsigned*)(h16 + (size_t)s0 * EMB + c);
            unsigned u1 = *(const unsigned*)(h16 + (size_t)s1 * EMB + c);
            unsigned u2 = *(const unsigned*)(h16 + (size_t)s2 * EMB + c);
            unsigned u3 = *(const unsigned*)(h16 + (size_t)s3 * EMB + c);
            unsigned u4 = *(const unsigned*)(h16 + (size_t)s4 * EMB + c);
            unsigned u5 = *(const unsigned*)(h16 + (size_t)s5 * EMB + c);
            unsigned u6 = *(const unsigned*)(h16 + (size_t)s6 * EMB + c);
            unsigned u7 = *(const unsigned*)(h16 + (size_t)s7 * EMB + c);
            unsigned u8 = *(const unsigned*)(h16 + (size_t)s8 * EMB + c);
            unsigned u9 = *(const unsigned*)(h16 + (size_t)s9 * EMB + c);
            unsigned ua = *(const unsigned*)(h16 + (size_t)sa * EMB + c);
            unsigned ub = *(const unsigned*)(h16 + (size_t)sb * EMB + c);
            unsigned uc = *(const unsigned*)(h16 + (size_t)sc * EMB + c);
            unsigned ud = *(const unsigned*)(h16 + (size_t)sd * EMB + c);
            unsigned ue = *(const unsigned*)(h16 + (size_t)se * EMB + c);
            unsigned uf = *(const unsigned*)(h16 + (size_t)sf * EMB + c);
            f16x2 pA = ((as_h2(u0) + as_h2(u1)) + (as_h2(u2) + as_h2(u3)))
                     + ((as_h2(u4) + as_h2(u5)) + (as_h2(u6) + as_h2(u7)));
            f16x2 pB = ((as_h2(u8) + as_h2(u9)) + (as_h2(ua) + as_h2(ub)))
                     + ((as_h2(uc) + as_h2(ud)) + (as_h2(ue) + as_h2(uf)));
            ax += (float)pA.x + (float)pB.x;
            ay += (float)pA.y + (float)pB.y;
        }
    };
    bulk16(eA, e1A, axA, ayA);
    bulk16(eB, e1B, axB, ayB);
    int nA = e1A - eA;   // 0..23
    int nB = e1B - eB;   // 0..23
    if (nA > 0 || nB > 0) {
        // clamp bases (srcc[0] fallback only for the impossible deg-0-at-row-0)
        int cbA = (e1A - 1 >= 0) ? e1A - 1 : 0;
        int cbB = (e1B - 1 >= 0) ? e1B - 1 : 0;
        // ---- burst 1: ALL index loads for both nodes
        IDXQ(A, 0)  IDXQ(A, 1)  IDXQ(A, 2)  IDXQ(A, 3)  IDXQ(A, 4)  IDXQ(A, 5)
        IDXQ(A, 6)  IDXQ(A, 7)  IDXQ(A, 8)  IDXQ(A, 9)  IDXQ(A, 10) IDXQ(A, 11)
        IDXQ(A, 12) IDXQ(A, 13) IDXQ(A, 14) IDXQ(A, 15) IDXQ(A, 16) IDXQ(A, 17)
        IDXQ(A, 18) IDXQ(A, 19) IDXQ(A, 20) IDXQ(A, 21) IDXQ(A, 22)
        IDXQ(B, 0)  IDXQ(B, 1)  IDXQ(B, 2)  IDXQ(B, 3)  IDXQ(B, 4)  IDXQ(B, 5)
        IDXQ(B, 6)  IDXQ(B, 7)  IDXQ(B, 8)  IDXQ(B, 9)  IDXQ(B, 10) IDXQ(B, 11)
        IDXQ(B, 12) IDXQ(B, 13) IDXQ(B, 14) IDXQ(B, 15) IDXQ(B, 16) IDXQ(B, 17)
        IDXQ(B, 18) IDXQ(B, 19) IDXQ(B, 20) IDXQ(B, 21) IDXQ(B, 22)
        // ---- burst 2: ALL gathers for both nodes
        GTHQ(A, 0)  GTHQ(A, 1)  GTHQ(A, 2)  GTHQ(A, 3)  GTHQ(A, 4)  GTHQ(A, 5)
        GTHQ(A, 6)  GTHQ(A, 7)  GTHQ(A, 8)  GTHQ(A, 9)  GTHQ(A, 10) GTHQ(A, 11)
        GTHQ(A, 12) GTHQ(A, 13) GTHQ(A, 14) GTHQ(A, 15) GTHQ(A, 16) GTHQ(A, 17)
        GTHQ(A, 18) GTHQ(A, 19) GTHQ(A, 20) GTHQ(A, 21) GTHQ(A, 22)
        GTHQ(B, 0)  GTHQ(B, 1)  GTHQ(B, 2)  GTHQ(B, 3)  GTHQ(B, 4)  GTHQ(B, 5)
        GTHQ(B, 6)  GTHQ(B, 7)  GTHQ(B, 8)  GTHQ(B, 9)  GTHQ(B, 10) GTHQ(B, 11)
        GTHQ(B, 12) GTHQ(B, 13) GTHQ(B, 14) GTHQ(B, 15) GTHQ(B, 16) GTHQ(B, 17)
        GTHQ(B, 18) GTHQ(B, 19) GTHQ(B, 20) GTHQ(B, 21) GTHQ(B, 22)
        // ---- accumulate A (exact r10 grouping)
        if (nA >= 16) {
            f16x2 pA = ((as_h2(uA0) + as_h2(uA1)) + (as_h2(uA2) + as_h2(uA3)))
                     + ((as_h2(uA4) + as_h2(uA5)) + (as_h2(uA6) + as_h2(uA7)));
            f16x2 pB2 = ((as_h2(uA8) + as_h2(uA9)) + (as_h2(uA10) + as_h2(uA11)))
                      + ((as_h2(uA12) + as_h2(uA13)) + (as_h2(uA14) + as_h2(uA15)));
            axA += (float)pA.x + (float)pB2.x;
            ayA += (float)pA.y + (float)pB2.y;
            ACCG(A, 16) ACCG(A, 17) ACCG(A, 18) ACCG(A, 19)
            ACCG(A, 20) ACCG(A, 21) ACCG(A, 22)
        } else if (nA >= 8) {
            f16x2 p07 = ((as_h2(uA0) + as_h2(uA1)) + (as_h2(uA2) + as_h2(uA3)))
                      + ((as_h2(uA4) + as_h2(uA5)) + (as_h2(uA6) + as_h2(uA7)));
            axA += (float)p07.x;
            ayA += (float)p07.y;
            ACCG(A, 8)  ACCG(A, 9)  ACCG(A, 10) ACCG(A, 11)
            ACCG(A, 12) ACCG(A, 13) ACCG(A, 14)
        } else if (nA >= 1) {
            ACCG(A, 0) ACCG(A, 1) ACCG(A, 2) ACCG(A, 3)
            ACCG(A, 4) ACCG(A, 5) ACCG(A, 6)
        }
        // ---- accumulate B
        if (nB >= 16) {
            f16x2 pA = ((as_h2(uB0) + as_h2(uB1)) + (as_h2(uB2) + as_h2(uB3)))
                     + ((as_h2(uB4) + as_h2(uB5)) + (as_h2(uB6) + as_h2(uB7)));
            f16x2 pB2 = ((as_h2(uB8) + as_h2(uB9)) + (as_h2(uB10) + as_h2(uB11)))
                      + ((as_h2(uB12) + as_h2(uB13)) + (as_h2(uB14) + as_h2(uB15)));
            axB += (float)pA.x + (float)pB2.x;
            ayB += (float)pA.y + (float)pB2.y;
            ACCG(B, 16) ACCG(B, 17) ACCG(B, 18) ACCG(B, 19)
            ACCG(B, 20) ACCG(B, 21) ACCG(B, 22)
        } else if (nB >= 8) {
            f16x2 p07 = ((as_h2(uB0) + as_h2(uB1)) + (as_h2(uB2) + as_h2(uB3)))
                      + ((as_h2(uB4) + as_h2(uB5)) + (as_h2(uB6) + as_h2(uB7)));
            axB += (float)p07.x;
            ayB += (float)p07.y;
            ACCG(B, 8)  ACCG(B, 9)  ACCG(B, 10) ACCG(B, 11)
            ACCG(B, 12) ACCG(B, 13) ACCG(B, 14)
        } else if (nB >= 1) {
            ACCG(B, 0) ACCG(B, 1) ACCG(B, 2) ACCG(B, 3)
            ACCG(B, 4) ACCG(B, 5) ACCG(B, 6)
        }
    }
    *(unsigned*)(agg16 + (size_t)vA * EMB + c) = pkh2(axA, ayA);
    *(unsigned*)(agg16 + (size_t)vB * EMB + c) = pkh2(axB, ayB);
}

// ---------------------------------------------------------------------------
// k_mlp (f16 MFMA), 64-row tile: activations single fp16 plane, weights
// fp16 hi/lo (2-term MFMA). LDS 51 KB -> 3 blocks/CU.
// D-frag: col=lane&15 (node), row=quad*4+reg. Writes z fp16; BN stats ->
// per-layer replicated buffers (blockIdx&31).
// ---------------------------------------------------------------------------
__global__ __launch_bounds__(256) void k_mlp(
        const unsigned short* __restrict__ agg16,
        const unsigned short* __restrict__ W1ph, const unsigned short* __restrict__ W1pl,
        const float* __restrict__ b1_l,
        const unsigned short* __restrict__ W2ph, const unsigned short* __restrict__ W2pl,
        const float* __restrict__ b2_l,
        unsigned short* __restrict__ z16, float* __restrict__ stats_l) {
    __shared__ unsigned short A16[64][136];    // 17 KB  (+8 pad)
    __shared__ unsigned short Hid16[64][264];  // 33.8 KB (+8 pad)
    int tid = threadIdx.x;
    int r0 = blockIdx.x * 64;
    int rep = blockIdx.x & (NREP - 1);
    // stage A tile (zero-pad rows >= NN): 1024 lane-16B loads = 4 iterations
    #pragma unroll
    for (int it = 0; it < 4; ++it) {
        int idx = it * 256 + tid;       // 0..1023
        int row = idx >> 4;
        int cb = (idx & 15) * 8;
        int grow = r0 + row;
        uint4 val = make_uint4(0u, 0u, 0u, 0u);
        if (grow < NN) val = *(const uint4*)(agg16 + (size_t)grow * EMB + cb);
        *(uint4*)(&A16[row][cb]) = val;
    }
    __syncthreads();
    int wave = tid >> 6, lane = tid & 63;
    int l16 = lane & 15, quad = lane >> 4;
    // ---- phase 1: wave owns hid cols [64*wave, 64*wave+64), all 64 rows
    {
        f16x8 af[4][4];
        #pragma unroll
        for (int nt = 0; nt < 4; ++nt)
            #pragma unroll
            for (int kk = 0; kk < 4; ++kk)
                af[nt][kk] = *(const f16x8*)(&A16[nt * 16 + l16][kk * 32 + quad * 8]);
        #pragma unroll
        for (int h2 = 0; h2 < 4; ++h2) {
            f16x8 whf[4], wlf[4];
            #pragma unroll
            for (int kk = 0; kk < 4; ++kk) {
                size_t off = ((((size_t)(wave * 4 + h2) * 4) + kk) * 64 + lane) * 8;
                whf[kk] = *(const f16x8*)(W1ph + off);
                wlf[kk] = *(const f16x8*)(W1pl + off);
            }
            float4 bv = *(const float4*)(b1_l + wave * 64 + h2 * 16 + quad * 4);
            f32x4 bias = {bv.x, bv.y, bv.z, bv.w};
            #pragma unroll
            for (int nt = 0; nt < 4; ++nt) {
                f32x4 acc = bias;
                #pragma unroll
                for (int kk = 0; kk < 4; ++kk)
                    acc = __builtin_amdgcn_mfma_f32_16x16x32_f16(whf[kk], af[nt][kk], acc, 0, 0, 0);
                #pragma unroll
                for (int kk = 0; kk < 4; ++kk)
                    acc = __builtin_amdgcn_mfma_f32_16x16x32_f16(wlf[kk], af[nt][kk], acc, 0, 0, 0);
                uint2 p;
                p.x = pkh2(fmaxf(acc[0], 0.f), fmaxf(acc[1], 0.f));
                p.y = pkh2(fmaxf(acc[2], 0.f), fmaxf(acc[3], 0.f));
                int col = wave * 64 + h2 * 16 + quad * 4;
                *(uint2*)(&Hid16[nt * 16 + l16][col]) = p;
            }
        }
    }
    __syncthreads();
    // ---- phase 2: wave owns out cols [32*wave, 32*wave+32), all 64 rows
    float ss[2][4] = {}, sq[2][4] = {};
    #pragma unroll
    for (int o2 = 0; o2 < 2; ++o2) {
        f16x8 w2h[8], w2l[8];
        #pragma unroll
        for (int kk = 0; kk < 8; ++kk) {
            size_t off = ((((size_t)(wave * 2 + o2) * 8) + kk) * 64 + lane) * 8;
            w2h[kk] = *(const f16x8*)(W2ph + off);
            w2l[kk] = *(const f16x8*)(W2pl + off);
        }
        float4 bv = *(const float4*)(b2_l + wave * 32 + o2 * 16 + quad * 4);
        f32x4 bias = {bv.x, bv.y, bv.z, bv.w};
        #pragma unroll
        for (int nt = 0; nt < 4; ++nt) {
            f16x8 hf[8];
            #pragma unroll
            for (int kk = 0; kk < 8; ++kk)
                hf[kk] = *(const f16x8*)(&Hid16[nt * 16 + l16][kk * 32 + quad * 8]);
            f32x4 acc = bias;
            #pragma unroll
            for (int kk = 0; kk < 8; ++kk)
                acc = __builtin_amdgcn_mfma_f32_16x16x32_f16(w2h[kk], hf[kk], acc, 0, 0, 0);
            #pragma unroll
            for (int kk = 0; kk < 8; ++kk)
                acc = __builtin_amdgcn_mfma_f32_16x16x32_f16(w2l[kk], hf[kk], acc, 0, 0, 0);
            int node = r0 + nt * 16 + l16;
            if (node < NN) {
                uint2 p = make_uint2(pkh2(acc[0], acc[1]), pkh2(acc[2], acc[3]));
                *(uint2*)(z16 + (size_t)node * EMB + wave * 32 + o2 * 16 + quad * 4) = p;
                #pragma unroll
                for (int r = 0; r < 4; ++r) {
                    ss[o2][r] += acc[r];
                    sq[o2][r] += acc[r] * acc[r];
                }
            }
        }
    }
    #pragma unroll
    for (int o2 = 0; o2 < 2; ++o2)
        #pragma unroll
        for (int r = 0; r < 4; ++r) {
            float s = ss[o2][r], q = sq[o2][r];
            #pragma unroll
            for (int m = 1; m < 16; m <<= 1) {
                s += __shfl_xor(s, m, 64);
                q += __shfl_xor(q, m, 64);
            }
            if (l16 == 0) {
                int oc = wave * 32 + o2 * 16 + quad * 4 + r;
                atomicAdd(&stats_l[rep * 2 * EMB + oc], s);
                atomicAdd(&stats_l[rep * 2 * EMB + EMB + oc], q);
            }
        }
}

// ---------------------------------------------------------------------------
// k_bnfused = k_bnscale + k_bn. Every block redundantly reduces the NREP
// stats replicas (32KB L2-hot reads) -> sc/sh in LDS, then applies BN
// (+ELU except last layer) grid-stride over z16.
// ---------------------------------------------------------------------------
__global__ void k_bnfused(const float* __restrict__ stats_l,
                          const float* __restrict__ gamma_l, const float* __restrict__ beta_l,
                          const unsigned short* __restrict__ z16,
                          unsigned short* __restrict__ h16, float* __restrict__ fout, int last) {
    __shared__ float red[2 * EMB];
    __shared__ float sc[EMB], sh[EMB];
    int tid = threadIdx.x;  // 256 == 2*EMB
    {
        float acc = 0.f;
        #pragma unroll
        for (int r = 0; r < NREP; ++r) acc += stats_l[r * 2 * EMB + tid];
        red[tid] = acc;
    }
    __syncthreads();
    if (tid < EMB) {
        float s = red[tid], q = red[EMB + tid];
        float mu = s * (1.f / NN);
        float var = q * (1.f / NN) - mu * mu;
        float sf = gamma_l[tid] * rsqrtf(var + BN_EPS);
        sc[tid] = sf;
        sh[tid] = beta_l[tid] - mu * sf;
    }
    __syncthreads();
    const int TOT = NN * EMB / 4;
    for (int gid = blockIdx.x * 256 + tid; gid < TOT; gid += gridDim.x * 256) {
        int c = (gid & 31) << 2;
        uint2 zp = *(const uint2*)(z16 + (size_t)gid * 4);
        float2 z01 = uph2(zp.x), z23 = uph2(zp.y);
        float o0 = z01.x * sc[c + 0] + sh[c + 0];
        float o1 = z01.y * sc[c + 1] + sh[c + 1];
        float o2 = z23.x * sc[c + 2] + sh[c + 2];
        float o3 = z23.y * sc[c + 3] + sh[c + 3];
        if (!last) {
            o0 = (o0 > 0.f) ? o0 : (__expf(o0) - 1.f);
            o1 = (o1 > 0.f) ? o1 : (__expf(o1) - 1.f);
            o2 = (o2 > 0.f) ? o2 : (__expf(o2) - 1.f);
            o3 = (o3 > 0.f) ? o3 : (__expf(o3) - 1.f);
            uint2 p = make_uint2(pkh2(o0, o1), pkh2(o2, o3));
            *(uint2*)(h16 + (size_t)gid * 4) = p;
        } else {
            *(float4*)(fout + (size_t)gid * 4) = make_float4(o0, o1, o2, o3);
        }
    }
}

// ---------------------------------------------------------------------------
extern "C" void kernel_launch(void* const* d_in, const int* in_sizes, int n_in,
                              void* d_out, int out_size, void* d_ws, size_t ws_size,
                              hipStream_t stream) {
    const float* x         = (const float*)d_in[0];
    const float* edge_attr = (const float*)d_in[1];
    const int*   edge_idx  = (const int*)d_in[2];
    const float* W_x   = (const float*)d_in[3];
    const float* b_x   = (const float*)d_in[4];
    const float* W_e   = (const float*)d_in[5];
    const float* b_e   = (const float*)d_in[6];
    const float* W1    = (const float*)d_in[7];
    const float* b1    = (const float*)d_in[8];
    const float* W2    = (const float*)d_in[9];
    const float* b2    = (const float*)d_in[10];
    const float* gamma = (const float*)d_in[11];
    const float* beta  = (const float*)d_in[12];
    float* fout = (float*)d_out;  // final BN writes fp32 here

    const int* src = edge_idx;
    const int* dst = edge_idx + NE;

    char* p = (char*)d_ws;
    auto alloc = [&](size_t bytes) { char* q = p; p += (bytes + 255) & ~(size_t)255; return q; };
    unsigned short* h16  = (unsigned short*)alloc((size_t)NN * EMB * 2);
    unsigned short* z16  = (unsigned short*)alloc((size_t)NN * EMB * 2);
    unsigned short* agg16 = (unsigned short*)alloc((size_t)NN * EMB * 2);
    unsigned short* W1ph = (unsigned short*)alloc((size_t)NL * HID * EMB * 2);
    unsigned short* W1pl = (unsigned short*)alloc((size_t)NL * HID * EMB * 2);
    unsigned short* W2ph = (unsigned short*)alloc((size_t)NL * EMB * HID * 2);
    unsigned short* W2pl = (unsigned short*)alloc((size_t)NL * EMB * HID * 2);
    int*   row_start  = (int*)alloc((NN + 1) * sizeof(int));
    int*   counts     = (int*)alloc(NN * sizeof(int));
    int*   cursor     = (int*)alloc(NN * sizeof(int));
    uint4* grouped    = (uint4*)alloc((size_t)NE * sizeof(uint4));
    uint4* sorted_pk  = (uint4*)alloc((size_t)NE * sizeof(uint4));
    int*   sorted_srcc= (int*)alloc((size_t)NE * sizeof(int));
    float* attsum     = (float*)alloc((size_t)NN * 8 * sizeof(float));
    int*   bsum       = (int*)alloc(SCAN_B * sizeof(int));
    int*   bpre       = (int*)alloc(SCAN_B * sizeof(int));
    int*   bcur       = (int*)alloc(NBUCK * sizeof(int));
    float* stats      = (float*)alloc((size_t)NL * NREP * 2 * EMB * sizeof(float));
    float* bsum_x     = (float*)alloc(EMB * sizeof(float));
    float* bsum_e     = (float*)alloc(NL * EMB * sizeof(float));

    k_prep<<<256, 256, 0, stream>>>(b_x, b_e, bsum_x, bsum_e, counts, cursor, stats);
    k_prepw<<<(2 * NL * EMB * HID + 255) / 256, 256, 0, stream>>>(W1, W2, W1ph, W1pl, W2ph, W2pl);
    k_init<<<(NN * 32 + 255) / 256, 256, 0, stream>>>(x, W_x, bsum_x, h16);
    k_hist<<<(NE + 255) / 256, 256, 0, stream>>>(dst, counts);
    k_scan1<<<SCAN_B, 256, 0, stream>>>(counts, bsum);
    k_scan2<<<1, 256, 0, stream>>>(bsum, bpre, row_start);
    k_scan3<<<SCAN_B, 256, 0, stream>>>(counts, bpre, row_start, bcur);
    k_bucket<<<(NE + BPB - 1) / BPB, 256, 0, stream>>>(src, dst, edge_attr, bcur, grouped);
    k_place<<<(NE + 255) / 256, 256, 0, stream>>>(grouped, row_start, cursor, sorted_pk);
    k_esum<<<SCAN_B, 256, 0, stream>>>(sorted_pk, row_start, attsum, sorted_srcc);
    const int AGG_GRID = ((NN / 2) * 64 + 255) / 256;   // 6250: one wave per node-pair
    for (int l = 0; l < NL; ++l) {
        float* stats_l = stats + (size_t)l * NREP * 2 * EMB;
        k_agg<<<AGG_GRID, 256, 0, stream>>>(
            h16, sorted_srcc, attsum,
            W_e + (size_t)l * EF * EMB, bsum_e + l * EMB, row_start,
            agg16);
        k_mlp<<<(NN + 63) / 64, 256, 0, stream>>>(
            agg16,
            W1ph + (size_t)l * HID * EMB, W1pl + (size_t)l * HID * EMB, b1 + (size_t)l * HID,
            W2ph + (size_t)l * EMB * HID, W2pl + (size_t)l * EMB * HID, b2 + (size_t)l * EMB,
            z16, stats_l);
        k_bnfused<<<2048, 256, 0, stream>>>(
            stats_l, gamma + l * EMB, beta + l * EMB, z16, h16, fout, (l == NL - 1) ? 1 : 0);
    }
}

// Round 18
// 519.820 us; speedup vs baseline: 1.0353x; 1.0353x over previous
//
#include <hip/hip_runtime.h>
#include <math.h>

#define NN 50000
#define NE 800000
#define EMB 128
#define HID 256
#define NF 7
#define EF 5
#define NL 5
#define BN_EPS 1e-5f
#define NREP 32     // stats replicas to kill same-line atomic serialization
#define SCAN_B 196  // ceil(NN/256)
#define NBUCK 49    // ceil(NN/1024) coarse dst-buckets for the 2-phase fill

typedef _Float16 f16x8 __attribute__((ext_vector_type(8)));
typedef _Float16 f16x2 __attribute__((ext_vector_type(2)));
typedef __attribute__((ext_vector_type(4))) float f32x4;

// fp16 pack/unpack
__device__ inline unsigned pkh2(float a, float b) {
    union { unsigned v; _Float16 h[2]; } x;
    x.h[0] = (_Float16)a; x.h[1] = (_Float16)b;
    return x.v;
}
__device__ inline float2 uph2(unsigned u) {
    union { unsigned v; _Float16 h[2]; } x; x.v = u;
    return make_float2((float)x.h[0], (float)x.h[1]);
}
__device__ inline unsigned short f2h_bits(float f) {
    _Float16 h = (_Float16)f;
    return __builtin_bit_cast(unsigned short, h);
}
__device__ inline float h_bits2f(unsigned short b) {
    return (float)__builtin_bit_cast(_Float16, b);
}
__device__ inline f16x2 as_h2(unsigned u) { return __builtin_bit_cast(f16x2, u); }

// ---------------------------------------------------------------------------
// k_prep: block 0 computes bias-sum vectors; all blocks zero CSR counts/cursor
// and ALL per-layer BN-stats replicas (zeroed once for all NL layers).
// ---------------------------------------------------------------------------
__global__ void k_prep(const float* __restrict__ b_x, const float* __restrict__ b_e,
                       float* __restrict__ bsum_x, float* __restrict__ bsum_e,
                       int* __restrict__ counts, int* __restrict__ cursor,
                       float* __restrict__ stats) {
    int tid = threadIdx.x;
    if (blockIdx.x == 0 && tid < EMB) {
        float s = 0.f;
        for (int f = 0; f < NF; ++f) s += b_x[f * EMB + tid];
        bsum_x[tid] = s;
        for (int l = 0; l < NL; ++l) {
            float se = 0.f;
            for (int f = 0; f < EF; ++f) se += b_e[(l * EF + f) * EMB + tid];
            bsum_e[l * EMB + tid] = se;
        }
    }
    int gid = blockIdx.x * blockDim.x + tid;
    int stride = gridDim.x * blockDim.x;
    for (int i = gid; i < NN; i += stride) { counts[i] = 0; cursor[i] = 0; }
    const int STOT = NL * NREP * 2 * EMB;
    for (int i = gid; i < STOT; i += stride) stats[i] = 0.f;
}

// ---------------------------------------------------------------------------
// k_prepw: fragment-pack + fp16 hi/lo split of weights (combined rel ~2^-22).
// W1p layout: [L][wave(4)][h2(4)][kk(4)][lane(64)][j(8)]  (lane-contiguous 16B)
// W2p layout: [L][wave(4)][o2(2)][kk(8)][lane(64)][j(8)]
// ---------------------------------------------------------------------------
__global__ void k_prepw(const float* __restrict__ W1, const float* __restrict__ W2,
                        unsigned short* __restrict__ W1ph, unsigned short* __restrict__ W1pl,
                        unsigned short* __restrict__ W2ph, unsigned short* __restrict__ W2pl) {
    const int TOT = NL * EMB * HID;   // 163840 per matrix
    int gid = blockIdx.x * blockDim.x + threadIdx.x;
    if (gid < TOT) {
        int l = gid / (EMB * HID);
        int r = gid % (EMB * HID);             // 32768
        int w = r >> 13;                       // /8192
        int rem = r & 8191;
        int h2 = rem >> 11;                    // /2048
        int rem2 = rem & 2047;
        int kk = rem2 >> 9;                    // /512
        int rem3 = rem2 & 511;
        int lane = rem3 >> 3;
        int j = rem3 & 7;
        int hc = w * 64 + h2 * 16 + (lane & 15);
        int k = kk * 32 + (lane >> 4) * 8 + j;
        float wv = W1[((size_t)l * EMB + k) * HID + hc];
        unsigned short hi = f2h_bits(wv);
        W1ph[gid] = hi;
        W1pl[gid] = f2h_bits(wv - h_bits2f(hi));
    } else if (gid < 2 * TOT) {
        int g = gid - TOT;
        int l = g / (EMB * HID);
        int r = g % (EMB * HID);
        int w = r >> 13;
        int rem = r & 8191;
        int o2 = rem >> 12;                    // /4096
        int rem2 = rem & 4095;
        int kk = rem2 >> 9;
        int rem3 = rem2 & 511;
        int lane = rem3 >> 3;
        int j = rem3 & 7;
        int oc = w * 32 + o2 * 16 + (lane & 15);
        int k2 = kk * 32 + (lane >> 4) * 8 + j;
        float wv = W2[((size_t)l * HID + k2) * EMB + oc];
        unsigned short hi = f2h_bits(wv);
        W2ph[g] = hi;
        W2pl[g] = f2h_bits(wv - h_bits2f(hi));
    }
}

// ---------------------------------------------------------------------------
// k_init: h(fp16) = x @ W_x + bsum_x  (32 threads/node, 4 cols each)
// ---------------------------------------------------------------------------
__global__ void k_init(const float* __restrict__ x, const float* __restrict__ W_x,
                       const float* __restrict__ bsum_x, unsigned short* __restrict__ h16) {
    int gid = blockIdx.x * blockDim.x + threadIdx.x;
    int v = gid >> 5;
    if (v >= NN) return;
    int c = (gid & 31) << 2;
    float4 acc = *(const float4*)(bsum_x + c);
    #pragma unroll
    for (int f = 0; f < NF; ++f) {
        float xv = x[(size_t)v * NF + f];
        float4 w = *(const float4*)(W_x + f * EMB + c);
        acc.x += xv * w.x; acc.y += xv * w.y; acc.z += xv * w.z; acc.w += xv * w.w;
    }
    uint2 p = make_uint2(pkh2(acc.x, acc.y), pkh2(acc.z, acc.w));
    *(uint2*)(h16 + (size_t)v * EMB + c) = p;
}

// ---------------------------------------------------------------------------
// CSR build: histogram of dst, 3-phase multi-block scan
// ---------------------------------------------------------------------------
__global__ void k_hist(const int* __restrict__ dst, int* __restrict__ counts) {
    int e = blockIdx.x * blockDim.x + threadIdx.x;
    if (e < NE) atomicAdd(&counts[dst[e]], 1);
}

__global__ void k_scan1(const int* __restrict__ counts, int* __restrict__ bsum) {
    int tid = threadIdx.x;
    int i = blockIdx.x * 256 + tid;
    int v = (i < NN) ? counts[i] : 0;
    #pragma unroll
    for (int off = 1; off < 64; off <<= 1) v += __shfl_xor(v, off, 64);
    __shared__ int ws[4];
    if ((tid & 63) == 0) ws[tid >> 6] = v;
    __syncthreads();
    if (tid == 0) bsum[blockIdx.x] = ws[0] + ws[1] + ws[2] + ws[3];
}

__global__ void k_scan2(const int* __restrict__ bsum, int* __restrict__ bpre,
                        int* __restrict__ row_start) {
    int tid = threadIdx.x;  // 256 threads
    int x = (tid < SCAN_B) ? bsum[tid] : 0;
    int lane = tid & 63, wv = tid >> 6;
    int v = x;
    #pragma unroll
    for (int off = 1; off < 64; off <<= 1) {
        int t = __shfl_up(v, off, 64);
        if (lane >= off) v += t;
    }
    __shared__ int wsum[4];
    if (lane == 63) wsum[wv] = v;
    __syncthreads();
    int woff = 0;
    #pragma unroll
    for (int w = 0; w < 4; ++w) if (w < wv) woff += wsum[w];
    int incl = v + woff;
    if (tid < SCAN_B) bpre[tid] = incl - x;
    if (tid == 255) row_start[NN] = incl;
}

// scan3 also seeds the coarse-bucket cursors: bcur[b] = row_start[b*1024]
__global__ void k_scan3(const int* __restrict__ counts, const int* __restrict__ bpre,
                        int* __restrict__ row_start, int* __restrict__ bcur) {
    int tid = threadIdx.x;
    int i = blockIdx.x * 256 + tid;
    int x = (i < NN) ? counts[i] : 0;
    int lane = tid & 63, wv = tid >> 6;
    int v = x;
    #pragma unroll
    for (int off = 1; off < 64; off <<= 1) {
        int t = __shfl_up(v, off, 64);
        if (lane >= off) v += t;
    }
    __shared__ int wsum[4];
    if (lane == 63) wsum[wv] = v;
    __syncthreads();
    int woff = 0;
    #pragma unroll
    for (int w = 0; w < 4; ++w) if (w < wv) woff += wsum[w];
    if (i < NN) {
        int rs = bpre[blockIdx.x] + v + woff - x;
        row_start[i] = rs;
        if ((i & 1023) == 0) bcur[i >> 10] = rs;
    }
}

// ---------------------------------------------------------------------------
// 2-phase fill: k_bucket = LDS-histogram radix partition into NBUCK coarse
// dst-buckets (contiguous appends, no sector amplification);
// k_place = scatter within an L2-resident ~200KB bucket range.
// Record: {src, h(a0,a1), h(a2,a3), h(a4) | dst<<16}  (dst < 2^16).
// ---------------------------------------------------------------------------
#define BPB 2048   // edges per block
__global__ __launch_bounds__(256) void k_bucket(
        const int* __restrict__ src, const int* __restrict__ dst,
        const float* __restrict__ edge_attr,
        int* __restrict__ bcur, uint4* __restrict__ grouped) {
    __shared__ int lcnt[NBUCK];
    __shared__ int lbase[NBUCK];
    int tid = threadIdx.x;
    if (tid < NBUCK) lcnt[tid] = 0;
    __syncthreads();
    int base = blockIdx.x * BPB;
    int b_[8];
    int d_[8];
    #pragma unroll
    for (int k = 0; k < 8; ++k) {
        int e = base + k * 256 + tid;
        if (e < NE) {
            int d = dst[e];
            d_[k] = d;
            b_[k] = d >> 10;
            atomicAdd(&lcnt[b_[k]], 1);
        } else b_[k] = -1;
    }
    __syncthreads();
    if (tid < NBUCK) {
        lbase[tid] = (lcnt[tid] > 0) ? atomicAdd(&bcur[tid], lcnt[tid]) : 0;
        lcnt[tid] = 0;
    }
    __syncthreads();
    #pragma unroll
    for (int k = 0; k < 8; ++k) {
        int e = base + k * 256 + tid;
        if (e < NE) {
            int b = b_[k];
            int off = lbase[b] + atomicAdd(&lcnt[b], 1);
            const float* ea = edge_attr + (size_t)e * EF;
            uint4 pk;
            pk.x = (unsigned)src[e];
            pk.y = pkh2(ea[0], ea[1]);
            pk.z = pkh2(ea[2], ea[3]);
            pk.w = (unsigned)f2h_bits(ea[4]) | ((unsigned)d_[k] << 16);
            grouped[off] = pk;
        }
    }
}

__global__ void k_place(const uint4* __restrict__ grouped,
                        const int* __restrict__ row_start, int* __restrict__ cursor,
                        uint4* __restrict__ sorted_pk) {
    int e = blockIdx.x * blockDim.x + threadIdx.x;
    if (e >= NE) return;
    uint4 pk = grouped[e];
    int d = (int)(pk.w >> 16);
    int pos = atomicAdd(&cursor[d], 1);
    sorted_pk[row_start[d] + pos] = pk;
}

// ---------------------------------------------------------------------------
// k_esum (once): per node, sum incoming edge attrs -> attsum[v][8] =
// {a0..a4, deg, 0, 0}; emit compact sorted_srcc[e] (sequential write).
// ---------------------------------------------------------------------------
__global__ void k_esum(const uint4* __restrict__ sorted_pk,
                       const int* __restrict__ row_start,
                       float* __restrict__ attsum, int* __restrict__ sorted_srcc) {
    int v = blockIdx.x * blockDim.x + threadIdx.x;
    if (v >= NN) return;
    int e0 = row_start[v], e1 = row_start[v + 1];
    float s0 = 0.f, s1 = 0.f, s2 = 0.f, s3 = 0.f, s4 = 0.f;
    for (int e = e0; e < e1; ++e) {
        uint4 pk = sorted_pk[e];
        sorted_srcc[e] = (int)pk.x;
        float2 a01 = uph2(pk.y), a23 = uph2(pk.z);
        s0 += a01.x; s1 += a01.y; s2 += a23.x; s3 += a23.y;
        s4 += h_bits2f((unsigned short)(pk.w & 0xffffu));
    }
    float* o = attsum + (size_t)v * 8;
    *(float4*)(o) = make_float4(s0, s1, s2, s3);
    *(float4*)(o + 4) = make_float4(s4, (float)(e1 - e0), 0.f, 0.f);
}

// ---------------------------------------------------------------------------
// k_agg (r10 form — BEST VERIFIED, 521.7us total): one wave per node,
// 2 cols/lane, readfirstlane'd SGPR-base gathers. Bulk 16-batches while
// >=24 edges remain; then a unified remainder burst (all index loads, then
// all gathers, then accumulate in the exact original tree16/tree8+guarded-
// serial order). r11's two-nodes-per-wave variant REGRESSED (538.2us):
// halving wave count cut chip-level TLP more than the deeper per-wave
// bursts gained — this gather scales with wave count, not per-wave depth.
// ---------------------------------------------------------------------------
__global__ __launch_bounds__(256) void k_agg(
        const unsigned short* __restrict__ h16, const int* __restrict__ sorted_srcc,
        const float* __restrict__ attsum,
        const float* __restrict__ W_e_l, const float* __restrict__ bsum_e_l,
        const int* __restrict__ row_start,
        unsigned short* __restrict__ agg16) {
    int tid = threadIdx.x;
    int gid = blockIdx.x * 256 + tid;
    int v = gid >> 6;
    if (v >= NN) return;
    int c = (gid & 63) << 1;
    float2 we0 = *(const float2*)(W_e_l + 0 * EMB + c);
    float2 we1 = *(const float2*)(W_e_l + 1 * EMB + c);
    float2 we2 = *(const float2*)(W_e_l + 2 * EMB + c);
    float2 we3 = *(const float2*)(W_e_l + 3 * EMB + c);
    float2 we4 = *(const float2*)(W_e_l + 4 * EMB + c);
    float2 bs = *(const float2*)(bsum_e_l + c);
    float2 hv = uph2(*(const unsigned*)(h16 + (size_t)v * EMB + c));
    const float* at = attsum + (size_t)v * 8;
    float4 a03 = *(const float4*)(at);
    float2 a45 = *(const float2*)(at + 4);   // a4, deg
    float ax = hv.x + (a45.y + 1.f) * bs.x
             + a03.x*we0.x + a03.y*we1.x + a03.z*we2.x + a03.w*we3.x + a45.x*we4.x;
    float ay = hv.y + (a45.y + 1.f) * bs.y
             + a03.x*we0.y + a03.y*we1.y + a03.z*we2.y + a03.w*we3.y + a45.x*we4.y;
    int e0 = row_start[v], e1 = row_start[v + 1];
    int e = e0;
    // bulk 16-batches while >=24 remain (same per-degree decomposition as
    // the old {>=16 16-batch, >=8 8-batch, serial} laddering)
    for (; e + 24 <= e1; e += 16) {
        int s0 = __builtin_amdgcn_readfirstlane(sorted_srcc[e + 0]);
        int s1 = __builtin_amdgcn_readfirstlane(sorted_srcc[e + 1]);
        int s2 = __builtin_amdgcn_readfirstlane(sorted_srcc[e + 2]);
        int s3 = __builtin_amdgcn_readfirstlane(sorted_srcc[e + 3]);
        int s4 = __builtin_amdgcn_readfirstlane(sorted_srcc[e + 4]);
        int s5 = __builtin_amdgcn_readfirstlane(sorted_srcc[e + 5]);
        int s6 = __builtin_amdgcn_readfirstlane(sorted_srcc[e + 6]);
        int s7 = __builtin_amdgcn_readfirstlane(sorted_srcc[e + 7]);
        int s8 = __builtin_amdgcn_readfirstlane(sorted_srcc[e + 8]);
        int s9 = __builtin_amdgcn_readfirstlane(sorted_srcc[e + 9]);
        int sa = __builtin_amdgcn_readfirstlane(sorted_srcc[e + 10]);
        int sb = __builtin_amdgcn_readfirstlane(sorted_srcc[e + 11]);
        int sc = __builtin_amdgcn_readfirstlane(sorted_srcc[e + 12]);
        int sd = __builtin_amdgcn_readfirstlane(sorted_srcc[e + 13]);
        int se = __builtin_amdgcn_readfirstlane(sorted_srcc[e + 14]);
        int sf = __builtin_amdgcn_readfirstlane(sorted_srcc[e + 15]);
        unsigned u0 = *(const unsigned*)(h16 + (size_t)s0 * EMB + c);
        unsigned u1 = *(const unsigned*)(h16 + (size_t)s1 * EMB + c);
        unsigned u2 = *(const unsigned*)(h16 + (size_t)s2 * EMB + c);
        unsigned u3 = *(const unsigned*)(h16 + (size_t)s3 * EMB + c);
        unsigned u4 = *(const unsigned*)(h16 + (size_t)s4 * EMB + c);
        unsigned u5 = *(const unsigned*)(h16 + (size_t)s5 * EMB + c);
        unsigned u6 = *(const unsigned*)(h16 + (size_t)s6 * EMB + c);
        unsigned u7 = *(const unsigned*)(h16 + (size_t)s7 * EMB + c);
        unsigned u8 = *(const unsigned*)(h16 + (size_t)s8 * EMB + c);
        unsigned u9 = *(const unsigned*)(h16 + (size_t)s9 * EMB + c);
        unsigned ua = *(const unsigned*)(h16 + (size_t)sa * EMB + c);
        unsigned ub = *(const unsigned*)(h16 + (size_t)sb * EMB + c);
        unsigned uc = *(const unsigned*)(h16 + (size_t)sc * EMB + c);
        unsigned ud = *(const unsigned*)(h16 + (size_t)sd * EMB + c);
        unsigned ue = *(const unsigned*)(h16 + (size_t)se * EMB + c);
        unsigned uf = *(const unsigned*)(h16 + (size_t)sf * EMB + c);
        f16x2 pA = ((as_h2(u0) + as_h2(u1)) + (as_h2(u2) + as_h2(u3)))
                 + ((as_h2(u4) + as_h2(u5)) + (as_h2(u6) + as_h2(u7)));
        f16x2 pB = ((as_h2(u8) + as_h2(u9)) + (as_h2(ua) + as_h2(ub)))
                 + ((as_h2(uc) + as_h2(ud)) + (as_h2(ue) + as_h2(uf)));
        ax += (float)pA.x + (float)pB.x;
        ay += (float)pA.y + (float)pB.y;
    }
    int n = e1 - e;   // 0..23
    if (n >= 16) {
        // one burst: 16 tree indices + 7 clamped serial indices, then all 23
        // gathers together; accumulate exactly as before.
        int last = e1 - 1;
        int s0 = __builtin_amdgcn_readfirstlane(sorted_srcc[e + 0]);
        int s1 = __builtin_amdgcn_readfirstlane(sorted_srcc[e + 1]);
        int s2 = __builtin_amdgcn_readfirstlane(sorted_srcc[e + 2]);
        int s3 = __builtin_amdgcn_readfirstlane(sorted_srcc[e + 3]);
        int s4 = __builtin_amdgcn_readfirstlane(sorted_srcc[e + 4]);
        int s5 = __builtin_amdgcn_readfirstlane(sorted_srcc[e + 5]);
        int s6 = __builtin_amdgcn_readfirstlane(sorted_srcc[e + 6]);
        int s7 = __builtin_amdgcn_readfirstlane(sorted_srcc[e + 7]);
        int s8 = __builtin_amdgcn_readfirstlane(sorted_srcc[e + 8]);
        int s9 = __builtin_amdgcn_readfirstlane(sorted_srcc[e + 9]);
        int sa = __builtin_amdgcn_readfirstlane(sorted_srcc[e + 10]);
        int sb = __builtin_amdgcn_readfirstlane(sorted_srcc[e + 11]);
        int sc = __builtin_amdgcn_readfirstlane(sorted_srcc[e + 12]);
        int sd = __builtin_amdgcn_readfirstlane(sorted_srcc[e + 13]);
        int se = __builtin_amdgcn_readfirstlane(sorted_srcc[e + 14]);
        int sf = __builtin_amdgcn_readfirstlane(sorted_srcc[e + 15]);
        int j0 = (e + 16 < e1) ? e + 16 : last;
        int j1 = (e + 17 < e1) ? e + 17 : last;
        int j2 = (e + 18 < e1) ? e + 18 : last;
        int j3 = (e + 19 < e1) ? e + 19 : last;
        int j4 = (e + 20 < e1) ? e + 20 : last;
        int j5 = (e + 21 < e1) ? e + 21 : last;
        int j6 = (e + 22 < e1) ? e + 22 : last;
        int t0 = __builtin_amdgcn_readfirstlane(sorted_srcc[j0]);
        int t1 = __builtin_amdgcn_readfirstlane(sorted_srcc[j1]);
        int t2 = __builtin_amdgcn_readfirstlane(sorted_srcc[j2]);
        int t3 = __builtin_amdgcn_readfirstlane(sorted_srcc[j3]);
        int t4 = __builtin_amdgcn_readfirstlane(sorted_srcc[j4]);
        int t5 = __builtin_amdgcn_readfirstlane(sorted_srcc[j5]);
        int t6 = __builtin_amdgcn_readfirstlane(sorted_srcc[j6]);
        unsigned u0 = *(const unsigned*)(h16 + (size_t)s0 * EMB + c);
        unsigned u1 = *(const unsigned*)(h16 + (size_t)s1 * EMB + c);
        unsigned u2 = *(const unsigned*)(h16 + (size_t)s2 * EMB + c);
        unsigned u3 = *(const unsigned*)(h16 + (size_t)s3 * EMB + c);
        unsigned u4 = *(const unsigned*)(h16 + (size_t)s4 * EMB + c);
        unsigned u5 = *(const unsigned*)(h16 + (size_t)s5 * EMB + c);
        unsigned u6 = *(const unsigned*)(h16 + (size_t)s6 * EMB + c);
        unsigned u7 = *(const unsigned*)(h16 + (size_t)s7 * EMB + c);
        unsigned u8 = *(const unsigned*)(h16 + (size_t)s8 * EMB + c);
        unsigned u9 = *(const unsigned*)(h16 + (size_t)s9 * EMB + c);
        unsigned ua = *(const unsigned*)(h16 + (size_t)sa * EMB + c);
        unsigned ub = *(const unsigned*)(h16 + (size_t)sb * EMB + c);
        unsigned uc = *(const unsigned*)(h16 + (size_t)sc * EMB + c);
        unsigned ud = *(const unsigned*)(h16 + (size_t)sd * EMB + c);
        unsigned ue = *(const unsigned*)(h16 + (size_t)se * EMB + c);
        unsigned uf = *(const unsigned*)(h16 + (size_t)sf * EMB + c);
        unsigned w0 = *(const unsigned*)(h16 + (size_t)t0 * EMB + c);
        unsigned w1 = *(const unsigned*)(h16 + (size_t)t1 * EMB + c);
        unsigned w2 = *(const unsigned*)(h16 + (size_t)t2 * EMB + c);
        unsigned w3 = *(const unsigned*)(h16 + (size_t)t3 * EMB + c);
        unsigned w4 = *(const unsigned*)(h16 + (size_t)t4 * EMB + c);
        unsigned w5 = *(const unsigned*)(h16 + (size_t)t5 * EMB + c);
        unsigned w6 = *(const unsigned*)(h16 + (size_t)t6 * EMB + c);
        f16x2 pA = ((as_h2(u0) + as_h2(u1)) + (as_h2(u2) + as_h2(u3)))
                 + ((as_h2(u4) + as_h2(u5)) + (as_h2(u6) + as_h2(u7)));
        f16x2 pB = ((as_h2(u8) + as_h2(u9)) + (as_h2(ua) + as_h2(ub)))
                 + ((as_h2(uc) + as_h2(ud)) + (as_h2(ue) + as_h2(uf)));
        ax += (float)pA.x + (float)pB.x;
        ay += (float)pA.y + (float)pB.y;
        float2 g0 = uph2(w0), g1 = uph2(w1), g2 = uph2(w2), g3 = uph2(w3);
        float2 g4 = uph2(w4), g5 = uph2(w5), g6 = uph2(w6);
        if (e + 16 < e1) { ax += g0.x; ay += g0.y; }
        if (e + 17 < e1) { ax += g1.x; ay += g1.y; }
        if (e + 18 < e1) { ax += g2.x; ay += g2.y; }
        if (e + 19 < e1) { ax += g3.x; ay += g3.y; }
        if (e + 20 < e1) { ax += g4.x; ay += g4.y; }
        if (e + 21 < e1) { ax += g5.x; ay += g5.y; }
        if (e + 22 < e1) { ax += g6.x; ay += g6.y; }
    } else if (n >= 8) {
        // one burst: 8 tree indices + 7 clamped serial indices
        int last = e1 - 1;
        int s0 = __builtin_amdgcn_readfirstlane(sorted_srcc[e + 0]);
        int s1 = __builtin_amdgcn_readfirstlane(sorted_srcc[e + 1]);
        int s2 = __builtin_amdgcn_readfirstlane(sorted_srcc[e + 2]);
        int s3 = __builtin_amdgcn_readfirstlane(sorted_srcc[e + 3]);
        int s4 = __builtin_amdgcn_readfirstlane(sorted_srcc[e + 4]);
        int s5 = __builtin_amdgcn_readfirstlane(sorted_srcc[e + 5]);
        int s6 = __builtin_amdgcn_readfirstlane(sorted_srcc[e + 6]);
        int s7 = __builtin_amdgcn_readfirstlane(sorted_srcc[e + 7]);
        int j0 = (e + 8  < e1) ? e + 8  : last;
        int j1 = (e + 9  < e1) ? e + 9  : last;
        int j2 = (e + 10 < e1) ? e + 10 : last;
        int j3 = (e + 11 < e1) ? e + 11 : last;
        int j4 = (e + 12 < e1) ? e + 12 : last;
        int j5 = (e + 13 < e1) ? e + 13 : last;
        int j6 = (e + 14 < e1) ? e + 14 : last;
        int t0 = __builtin_amdgcn_readfirstlane(sorted_srcc[j0]);
        int t1 = __builtin_amdgcn_readfirstlane(sorted_srcc[j1]);
        int t2 = __builtin_amdgcn_readfirstlane(sorted_srcc[j2]);
        int t3 = __builtin_amdgcn_readfirstlane(sorted_srcc[j3]);
        int t4 = __builtin_amdgcn_readfirstlane(sorted_srcc[j4]);
        int t5 = __builtin_amdgcn_readfirstlane(sorted_srcc[j5]);
        int t6 = __builtin_amdgcn_readfirstlane(sorted_srcc[j6]);
        unsigned u0 = *(const unsigned*)(h16 + (size_t)s0 * EMB + c);
        unsigned u1 = *(const unsigned*)(h16 + (size_t)s1 * EMB + c);
        unsigned u2 = *(const unsigned*)(h16 + (size_t)s2 * EMB + c);
        unsigned u3 = *(const unsigned*)(h16 + (size_t)s3 * EMB + c);
        unsigned u4 = *(const unsigned*)(h16 + (size_t)s4 * EMB + c);
        unsigned u5 = *(const unsigned*)(h16 + (size_t)s5 * EMB + c);
        unsigned u6 = *(const unsigned*)(h16 + (size_t)s6 * EMB + c);
        unsigned u7 = *(const unsigned*)(h16 + (size_t)s7 * EMB + c);
        unsigned w0 = *(const unsigned*)(h16 + (size_t)t0 * EMB + c);
        unsigned w1 = *(const unsigned*)(h16 + (size_t)t1 * EMB + c);
        unsigned w2 = *(const unsigned*)(h16 + (size_t)t2 * EMB + c);
        unsigned w3 = *(const unsigned*)(h16 + (size_t)t3 * EMB + c);
        unsigned w4 = *(const unsigned*)(h16 + (size_t)t4 * EMB + c);
        unsigned w5 = *(const unsigned*)(h16 + (size_t)t5 * EMB + c);
        unsigned w6 = *(const unsigned*)(h16 + (size_t)t6 * EMB + c);
        f16x2 p07 = ((as_h2(u0) + as_h2(u1)) + (as_h2(u2) + as_h2(u3)))
                  + ((as_h2(u4) + as_h2(u5)) + (as_h2(u6) + as_h2(u7)));
        ax += (float)p07.x;
        ay += (float)p07.y;
        float2 g0 = uph2(w0), g1 = uph2(w1), g2 = uph2(w2), g3 = uph2(w3);
        float2 g4 = uph2(w4), g5 = uph2(w5), g6 = uph2(w6);
        if (e + 8  < e1) { ax += g0.x; ay += g0.y; }
        if (e + 9  < e1) { ax += g1.x; ay += g1.y; }
        if (e + 10 < e1) { ax += g2.x; ay += g2.y; }
        if (e + 11 < e1) { ax += g3.x; ay += g3.y; }
        if (e + 12 < e1) { ax += g4.x; ay += g4.y; }
        if (e + 13 < e1) { ax += g5.x; ay += g5.y; }
        if (e + 14 < e1) { ax += g6.x; ay += g6.y; }
    } else if (n >= 1) {
        // parallel-issue serial tail (r9): clamp-load <=7 indices + gathers
        int last = e1 - 1;
        int i1 = (e + 1 < e1) ? e + 1 : last;
        int i2 = (e + 2 < e1) ? e + 2 : last;
        int i3 = (e + 3 < e1) ? e + 3 : last;
        int i4 = (e + 4 < e1) ? e + 4 : last;
        int i5 = (e + 5 < e1) ? e + 5 : last;
        int i6 = (e + 6 < e1) ? e + 6 : last;
        int s0 = __builtin_amdgcn_readfirstlane(sorted_srcc[e]);
        int s1 = __builtin_amdgcn_readfirstlane(sorted_srcc[i1]);
        int s2 = __builtin_amdgcn_readfirstlane(sorted_srcc[i2]);
        int s3 = __builtin_amdgcn_readfirstlane(sorted_srcc[i3]);
        int s4 = __builtin_amdgcn_readfirstlane(sorted_srcc[i4]);
        int s5 = __builtin_amdgcn_readfirstlane(sorted_srcc[i5]);
        int s6 = __builtin_amdgcn_readfirstlane(sorted_srcc[i6]);
        unsigned u0 = *(const unsigned*)(h16 + (size_t)s0 * EMB + c);
        unsigned u1 = *(const unsigned*)(h16 + (size_t)s1 * EMB + c);
        unsigned u2 = *(const unsigned*)(h16 + (size_t)s2 * EMB + c);
        unsigned u3 = *(const unsigned*)(h16 + (size_t)s3 * EMB + c);
        unsigned u4 = *(const unsigned*)(h16 + (size_t)s4 * EMB + c);
        unsigned u5 = *(const unsigned*)(h16 + (size_t)s5 * EMB + c);
        unsigned u6 = *(const unsigned*)(h16 + (size_t)s6 * EMB + c);
        float2 h0 = uph2(u0), h1 = uph2(u1), h2 = uph2(u2), h3 = uph2(u3);
        float2 h4 = uph2(u4), h5 = uph2(u5), h6 = uph2(u6);
        { ax += h0.x; ay += h0.y; }
        if (e + 1 < e1) { ax += h1.x; ay += h1.y; }
        if (e + 2 < e1) { ax += h2.x; ay += h2.y; }
        if (e + 3 < e1) { ax += h3.x; ay += h3.y; }
        if (e + 4 < e1) { ax += h4.x; ay += h4.y; }
        if (e + 5 < e1) { ax += h5.x; ay += h5.y; }
        if (e + 6 < e1) { ax += h6.x; ay += h6.y; }
    }
    *(unsigned*)(agg16 + (size_t)v * EMB + c) = pkh2(ax, ay);
}

// ---------------------------------------------------------------------------
// k_mlp (f16 MFMA), 64-row tile: activations single fp16 plane, weights
// fp16 hi/lo (2-term MFMA). LDS 51 KB -> 3 blocks/CU.
// D-frag: col=lane&15 (node), row=quad*4+reg. Writes z fp16; BN stats ->
// per-layer replicated buffers (blockIdx&31).
// ---------------------------------------------------------------------------
__global__ __launch_bounds__(256) void k_mlp(
        const unsigned short* __restrict__ agg16,
        const unsigned short* __restrict__ W1ph, const unsigned short* __restrict__ W1pl,
        const float* __restrict__ b1_l,
        const unsigned short* __restrict__ W2ph, const unsigned short* __restrict__ W2pl,
        const float* __restrict__ b2_l,
        unsigned short* __restrict__ z16, float* __restrict__ stats_l) {
    __shared__ unsigned short A16[64][136];    // 17 KB  (+8 pad)
    __shared__ unsigned short Hid16[64][264];  // 33.8 KB (+8 pad)
    int tid = threadIdx.x;
    int r0 = blockIdx.x * 64;
    int rep = blockIdx.x & (NREP - 1);
    // stage A tile (zero-pad rows >= NN): 1024 lane-16B loads = 4 iterations
    #pragma unroll
    for (int it = 0; it < 4; ++it) {
        int idx = it * 256 + tid;       // 0..1023
        int row = idx >> 4;
        int cb = (idx & 15) * 8;
        int grow = r0 + row;
        uint4 val = make_uint4(0u, 0u, 0u, 0u);
        if (grow < NN) val = *(const uint4*)(agg16 + (size_t)grow * EMB + cb);
        *(uint4*)(&A16[row][cb]) = val;
    }
    __syncthreads();
    int wave = tid >> 6, lane = tid & 63;
    int l16 = lane & 15, quad = lane >> 4;
    // ---- phase 1: wave owns hid cols [64*wave, 64*wave+64), all 64 rows
    {
        f16x8 af[4][4];
        #pragma unroll
        for (int nt = 0; nt < 4; ++nt)
            #pragma unroll
            for (int kk = 0; kk < 4; ++kk)
                af[nt][kk] = *(const f16x8*)(&A16[nt * 16 + l16][kk * 32 + quad * 8]);
        #pragma unroll
        for (int h2 = 0; h2 < 4; ++h2) {
            f16x8 whf[4], wlf[4];
            #pragma unroll
            for (int kk = 0; kk < 4; ++kk) {
                size_t off = ((((size_t)(wave * 4 + h2) * 4) + kk) * 64 + lane) * 8;
                whf[kk] = *(const f16x8*)(W1ph + off);
                wlf[kk] = *(const f16x8*)(W1pl + off);
            }
            float4 bv = *(const float4*)(b1_l + wave * 64 + h2 * 16 + quad * 4);
            f32x4 bias = {bv.x, bv.y, bv.z, bv.w};
            #pragma unroll
            for (int nt = 0; nt < 4; ++nt) {
                f32x4 acc = bias;
                #pragma unroll
                for (int kk = 0; kk < 4; ++kk)
                    acc = __builtin_amdgcn_mfma_f32_16x16x32_f16(whf[kk], af[nt][kk], acc, 0, 0, 0);
                #pragma unroll
                for (int kk = 0; kk < 4; ++kk)
                    acc = __builtin_amdgcn_mfma_f32_16x16x32_f16(wlf[kk], af[nt][kk], acc, 0, 0, 0);
                uint2 p;
                p.x = pkh2(fmaxf(acc[0], 0.f), fmaxf(acc[1], 0.f));
                p.y = pkh2(fmaxf(acc[2], 0.f), fmaxf(acc[3], 0.f));
                int col = wave * 64 + h2 * 16 + quad * 4;
                *(uint2*)(&Hid16[nt * 16 + l16][col]) = p;
            }
        }
    }
    __syncthreads();
    // ---- phase 2: wave owns out cols [32*wave, 32*wave+32), all 64 rows
    float ss[2][4] = {}, sq[2][4] = {};
    #pragma unroll
    for (int o2 = 0; o2 < 2; ++o2) {
        f16x8 w2h[8], w2l[8];
        #pragma unroll
        for (int kk = 0; kk < 8; ++kk) {
            size_t off = ((((size_t)(wave * 2 + o2) * 8) + kk) * 64 + lane) * 8;
            w2h[kk] = *(const f16x8*)(W2ph + off);
            w2l[kk] = *(const f16x8*)(W2pl + off);
        }
        float4 bv = *(const float4*)(b2_l + wave * 32 + o2 * 16 + quad * 4);
        f32x4 bias = {bv.x, bv.y, bv.z, bv.w};
        #pragma unroll
        for (int nt = 0; nt < 4; ++nt) {
            f16x8 hf[8];
            #pragma unroll
            for (int kk = 0; kk < 8; ++kk)
                hf[kk] = *(const f16x8*)(&Hid16[nt * 16 + l16][kk * 32 + quad * 8]);
            f32x4 acc = bias;
            #pragma unroll
            for (int kk = 0; kk < 8; ++kk)
                acc = __builtin_amdgcn_mfma_f32_16x16x32_f16(w2h[kk], hf[kk], acc, 0, 0, 0);
            #pragma unroll
            for (int kk = 0; kk < 8; ++kk)
                acc = __builtin_amdgcn_mfma_f32_16x16x32_f16(w2l[kk], hf[kk], acc, 0, 0, 0);
            int node = r0 + nt * 16 + l16;
            if (node < NN) {
                uint2 p = make_uint2(pkh2(acc[0], acc[1]), pkh2(acc[2], acc[3]));
                *(uint2*)(z16 + (size_t)node * EMB + wave * 32 + o2 * 16 + quad * 4) = p;
                #pragma unroll
                for (int r = 0; r < 4; ++r) {
                    ss[o2][r] += acc[r];
                    sq[o2][r] += acc[r] * acc[r];
                }
            }
        }
    }
    #pragma unroll
    for (int o2 = 0; o2 < 2; ++o2)
        #pragma unroll
        for (int r = 0; r < 4; ++r) {
            float s = ss[o2][r], q = sq[o2][r];
            #pragma unroll
            for (int m = 1; m < 16; m <<= 1) {
                s += __shfl_xor(s, m, 64);
                q += __shfl_xor(q, m, 64);
            }
            if (l16 == 0) {
                int oc = wave * 32 + o2 * 16 + quad * 4 + r;
                atomicAdd(&stats_l[rep * 2 * EMB + oc], s);
                atomicAdd(&stats_l[rep * 2 * EMB + EMB + oc], q);
            }
        }
}

// ---------------------------------------------------------------------------
// k_bnfused = k_bnscale + k_bn. Every block redundantly reduces the NREP
// stats replicas (32KB L2-hot reads) -> sc/sh in LDS, then applies BN
// (+ELU except last layer) grid-stride over z16.
// ---------------------------------------------------------------------------
__global__ void k_bnfused(const float* __restrict__ stats_l,
                          const float* __restrict__ gamma_l, const float* __restrict__ beta_l,
                          const unsigned short* __restrict__ z16,
                          unsigned short* __restrict__ h16, float* __restrict__ fout, int last) {
    __shared__ float red[2 * EMB];
    __shared__ float sc[EMB], sh[EMB];
    int tid = threadIdx.x;  // 256 == 2*EMB
    {
        float acc = 0.f;
        #pragma unroll
        for (int r = 0; r < NREP; ++r) acc += stats_l[r * 2 * EMB + tid];
        red[tid] = acc;
    }
    __syncthreads();
    if (tid < EMB) {
        float s = red[tid], q = red[EMB + tid];
        float mu = s * (1.f / NN);
        float var = q * (1.f / NN) - mu * mu;
        float sf = gamma_l[tid] * rsqrtf(var + BN_EPS);
        sc[tid] = sf;
        sh[tid] = beta_l[tid] - mu * sf;
    }
    __syncthreads();
    const int TOT = NN * EMB / 4;
    for (int gid = blockIdx.x * 256 + tid; gid < TOT; gid += gridDim.x * 256) {
        int c = (gid & 31) << 2;
        uint2 zp = *(const uint2*)(z16 + (size_t)gid * 4);
        float2 z01 = uph2(zp.x), z23 = uph2(zp.y);
        float o0 = z01.x * sc[c + 0] + sh[c + 0];
        float o1 = z01.y * sc[c + 1] + sh[c + 1];
        float o2 = z23.x * sc[c + 2] + sh[c + 2];
        float o3 = z23.y * sc[c + 3] + sh[c + 3];
        if (!last) {
            o0 = (o0 > 0.f) ? o0 : (__expf(o0) - 1.f);
            o1 = (o1 > 0.f) ? o1 : (__expf(o1) - 1.f);
            o2 = (o2 > 0.f) ? o2 : (__expf(o2) - 1.f);
            o3 = (o3 > 0.f) ? o3 : (__expf(o3) - 1.f);
            uint2 p = make_uint2(pkh2(o0, o1), pkh2(o2, o3));
            *(uint2*)(h16 + (size_t)gid * 4) = p;
        } else {
            *(float4*)(fout + (size_t)gid * 4) = make_float4(o0, o1, o2, o3);
        }
    }
}

// ---------------------------------------------------------------------------
extern "C" void kernel_launch(void* const* d_in, const int* in_sizes, int n_in,
                              void* d_out, int out_size, void* d_ws, size_t ws_size,
                              hipStream_t stream) {
    const float* x         = (const float*)d_in[0];
    const float* edge_attr = (const float*)d_in[1];
    const int*   edge_idx  = (const int*)d_in[2];
    const float* W_x   = (const float*)d_in[3];
    const float* b_x   = (const float*)d_in[4];
    const float* W_e   = (const float*)d_in[5];
    const float* b_e   = (const float*)d_in[6];
    const float* W1    = (const float*)d_in[7];
    const float* b1    = (const float*)d_in[8];
    const float* W2    = (const float*)d_in[9];
    const float* b2    = (const float*)d_in[10];
    const float* gamma = (const float*)d_in[11];
    const float* beta  = (const float*)d_in[12];
    float* fout = (float*)d_out;  // final BN writes fp32 here

    const int* src = edge_idx;
    const int* dst = edge_idx + NE;

    char* p = (char*)d_ws;
    auto alloc = [&](size_t bytes) { char* q = p; p += (bytes + 255) & ~(size_t)255; return q; };
    unsigned short* h16  = (unsigned short*)alloc((size_t)NN * EMB * 2);
    unsigned short* z16  = (unsigned short*)alloc((size_t)NN * EMB * 2);
    unsigned short* agg16 = (unsigned short*)alloc((size_t)NN * EMB * 2);
    unsigned short* W1ph = (unsigned short*)alloc((size_t)NL * HID * EMB * 2);
    unsigned short* W1pl = (unsigned short*)alloc((size_t)NL * HID * EMB * 2);
    unsigned short* W2ph = (unsigned short*)alloc((size_t)NL * EMB * HID * 2);
    unsigned short* W2pl = (unsigned short*)alloc((size_t)NL * EMB * HID * 2);
    int*   row_start  = (int*)alloc((NN + 1) * sizeof(int));
    int*   counts     = (int*)alloc(NN * sizeof(int));
    int*   cursor     = (int*)alloc(NN * sizeof(int));
    uint4* grouped    = (uint4*)alloc((size_t)NE * sizeof(uint4));
    uint4* sorted_pk  = (uint4*)alloc((size_t)NE * sizeof(uint4));
    int*   sorted_srcc= (int*)alloc((size_t)NE * sizeof(int));
    float* attsum     = (float*)alloc((size_t)NN * 8 * sizeof(float));
    int*   bsum       = (int*)alloc(SCAN_B * sizeof(int));
    int*   bpre       = (int*)alloc(SCAN_B * sizeof(int));
    int*   bcur       = (int*)alloc(NBUCK * sizeof(int));
    float* stats      = (float*)alloc((size_t)NL * NREP * 2 * EMB * sizeof(float));
    float* bsum_x     = (float*)alloc(EMB * sizeof(float));
    float* bsum_e     = (float*)alloc(NL * EMB * sizeof(float));

    k_prep<<<256, 256, 0, stream>>>(b_x, b_e, bsum_x, bsum_e, counts, cursor, stats);
    k_prepw<<<(2 * NL * EMB * HID + 255) / 256, 256, 0, stream>>>(W1, W2, W1ph, W1pl, W2ph, W2pl);
    k_init<<<(NN * 32 + 255) / 256, 256, 0, stream>>>(x, W_x, bsum_x, h16);
    k_hist<<<(NE + 255) / 256, 256, 0, stream>>>(dst, counts);
    k_scan1<<<SCAN_B, 256, 0, stream>>>(counts, bsum);
    k_scan2<<<1, 256, 0, stream>>>(bsum, bpre, row_start);
    k_scan3<<<SCAN_B, 256, 0, stream>>>(counts, bpre, row_start, bcur);
    k_bucket<<<(NE + BPB - 1) / BPB, 256, 0, stream>>>(src, dst, edge_attr, bcur, grouped);
    k_place<<<(NE + 255) / 256, 256, 0, stream>>>(grouped, row_start, cursor, sorted_pk);
    k_esum<<<SCAN_B, 256, 0, stream>>>(sorted_pk, row_start, attsum, sorted_srcc);
    const int AGG_GRID = (NN * 64 + 255) / 256;
    for (int l = 0; l < NL; ++l) {
        float* stats_l = stats + (size_t)l * NREP * 2 * EMB;
        k_agg<<<AGG_GRID, 256, 0, stream>>>(
            h16, sorted_srcc, attsum,
            W_e + (size_t)l * EF * EMB, bsum_e + l * EMB, row_start,
            agg16);
        k_mlp<<<(NN + 63) / 64, 256, 0, stream>>>(
            agg16,
            W1ph + (size_t)l * HID * EMB, W1pl + (size_t)l * HID * EMB, b1 + (size_t)l * HID,
            W2ph + (size_t)l * EMB * HID, W2pl + (size_t)l * EMB * HID, b2 + (size_t)l * EMB,
            z16, stats_l);
        k_bnfused<<<2048, 256, 0, stream>>>(
            stats_l, gamma + l * EMB, beta + l * EMB, z16, h16, fout, (l == NL - 1) ? 1 : 0);
    }
}